// Round 22
// baseline (256.294 us; speedup 1.0000x reference)
//
#include <hip/hip_runtime.h>
#include <hip/hip_bf16.h>

typedef __bf16 bf16_t;
typedef __bf16 bf16x8 __attribute__((ext_vector_type(8)));
typedef __bf16 bf16x4 __attribute__((ext_vector_type(4)));
typedef float f32x4 __attribute__((ext_vector_type(4)));
typedef unsigned int u32;

#define MFMA16 __builtin_amdgcn_mfma_f32_16x16x32_bf16
static constexpr float MASKV = -1.0e30f;
static constexpr int Sdim = 1024;

__device__ __forceinline__ void gload16(const void* g, void* l) {
    __builtin_amdgcn_global_load_lds((const __attribute__((address_space(1))) u32*)g,
                                     (__attribute__((address_space(3))) u32*)l, 16, 0, 0);
}

__device__ __forceinline__ void splt2(float v, bf16_t* h, bf16_t* l) {
    const bf16_t hv = (bf16_t)v;
    *h = hv; *l = (bf16_t)(v - (float)hv);
}

// ---- split f32 inputs into bf16 hi/lo planes (x, W_qkv) + bf16 W_proj ----
static constexpr int QX = 1048576;
static constexpr int QW = 786432;

__global__ __launch_bounds__(256) void split2_k(
    const float* __restrict__ x, const float* __restrict__ wqkv, const float* __restrict__ wproj,
    bf16_t* __restrict__ xh, bf16_t* __restrict__ xl,
    bf16_t* __restrict__ wh, bf16_t* __restrict__ wl, bf16_t* __restrict__ wp)
{
    int q = blockIdx.x * 256 + threadIdx.x;
    const int stride = 2048 * 256;
#pragma unroll
    for (int it = 0; it < 4; ++it, q += stride) {
        if (q < QX + QW) {
            const float* src; bf16_t *dh, *dl;
            if (q < QX) { src = x + (size_t)q * 4; dh = xh + (size_t)q * 4; dl = xl + (size_t)q * 4; }
            else { const int r = q - QX; src = wqkv + (size_t)r * 4; dh = wh + (size_t)r * 4; dl = wl + (size_t)r * 4; }
            const f32x4 v = *(const f32x4*)src;
            bf16x4 hv, lv;
#pragma unroll
            for (int c = 0; c < 4; ++c) { bf16_t a, b; splt2(v[c], &a, &b); hv[c] = a; lv[c] = b; }
            *(bf16x4*)dh = hv; *(bf16x4*)dl = lv;
        } else {
            const int r = q - QX - QW;
            const f32x4 v = *(const f32x4*)(wproj + (size_t)r * 4);
            bf16x4 hv;
#pragma unroll
            for (int c = 0; c < 4; ++c) hv[c] = (bf16_t)v[c];
            *(bf16x4*)(wp + (size_t)r * 4) = hv;
        }
    }
}

// ---- QKV GEMM: hi/lo 3-product for Q/K -> PRE-SPLIT bf16 planes; V -> bf16 T ----
__global__ __launch_bounds__(256) void gemm_qkv(
    const bf16_t* __restrict__ Ah_g, const bf16_t* __restrict__ Al_g,
    const bf16_t* __restrict__ Bh_g, const bf16_t* __restrict__ Bl_g,
    bf16_t* __restrict__ Qhi, bf16_t* __restrict__ Qlo,
    bf16_t* __restrict__ Khi, bf16_t* __restrict__ Klo, bf16_t* __restrict__ Vt)
{
    __shared__ bf16_t Ah[128 * 32], Al[128 * 32], Bh[128 * 32], Bl[128 * 32];
    const int tid = threadIdx.x, w = tid >> 6, lane = tid & 63;
    const int lm = lane & 15, hi = lane >> 4;
    const int wr = w >> 1, wc = w & 1;
    const int m0 = blockIdx.x * 128, n0 = blockIdx.y * 128;
    const int isel = n0 >> 10;
    const bool three = (isel < 2);

    f32x4 acc[4][4] = {};

    for (int kt = 0; kt < 32; ++kt) {
        __syncthreads();
#pragma unroll
        for (int c = 0; c < 2; ++c) {
            const int j = c * 256 + tid;
            const int r = j >> 2, cg = (j & 3) << 3;
            const int base = (c * 256 + w * 64) * 8;
            const size_t goa = (size_t)(m0 + r) * 1024 + kt * 32 + cg;
            const size_t gob = (size_t)(n0 + r) * 1024 + kt * 32 + cg;
            gload16(Ah_g + goa, &Ah[base]);
            gload16(Bh_g + gob, &Bh[base]);
            if (three) {
                gload16(Al_g + goa, &Al[base]);
                gload16(Bl_g + gob, &Bl[base]);
            }
        }
        __syncthreads();

        bf16x8 ah[4], bh[4], al[4], bl[4];
#pragma unroll
        for (int mi = 0; mi < 4; ++mi)
            ah[mi] = *(const bf16x8*)&Ah[(wr * 64 + mi * 16 + lm) * 32 + hi * 8];
#pragma unroll
        for (int ni = 0; ni < 4; ++ni)
            bh[ni] = *(const bf16x8*)&Bh[(wc * 64 + ni * 16 + lm) * 32 + hi * 8];
        if (three) {
#pragma unroll
            for (int mi = 0; mi < 4; ++mi)
                al[mi] = *(const bf16x8*)&Al[(wr * 64 + mi * 16 + lm) * 32 + hi * 8];
#pragma unroll
            for (int ni = 0; ni < 4; ++ni)
                bl[ni] = *(const bf16x8*)&Bl[(wc * 64 + ni * 16 + lm) * 32 + hi * 8];
        }
#pragma unroll
        for (int mi = 0; mi < 4; ++mi)
#pragma unroll
            for (int ni = 0; ni < 4; ++ni) {
                if (three) {
                    acc[mi][ni] = MFMA16(ah[mi], bl[ni], acc[mi][ni], 0, 0, 0);
                    acc[mi][ni] = MFMA16(al[mi], bh[ni], acc[mi][ni], 0, 0, 0);
                }
                acc[mi][ni] = MFMA16(ah[mi], bh[ni], acc[mi][ni], 0, 0, 0);
            }
    }

#pragma unroll
    for (int mi = 0; mi < 4; ++mi)
#pragma unroll
        for (int ni = 0; ni < 4; ++ni)
#pragma unroll
            for (int j = 0; j < 4; ++j) {
                const float v = acc[mi][ni][j];
                const int m = m0 + wr * 64 + mi * 16 + hi * 4 + j;
                const int e = n0 + wc * 64 + ni * 16 + lm;
                const int b = m >> 10, s = m & 1023;
                const int h = (e >> 6) & 15, dh = e & 63;
                if (isel < 2) {
                    const size_t off = (((size_t)(b * 16 + h)) * Sdim + s) * 64 + dh;
                    bf16_t hv, lv; splt2(v, &hv, &lv);
                    if (isel == 0) { Qhi[off] = hv; Qlo[off] = lv; }
                    else           { Khi[off] = hv; Klo[off] = lv; }
                } else {
                    Vt[(((size_t)(b * 16 + h)) * 64 + dh) * Sdim + s] = (bf16_t)v;
                }
            }
}

// ---- fused attention: spread writes (phase-A zero-fill), bounded softmax ----
__global__ __launch_bounds__(256) void attn_k(
    const bf16_t* __restrict__ Qhi, const bf16_t* __restrict__ Qlo,
    const bf16_t* __restrict__ Khi, const bf16_t* __restrict__ Klo,
    const bf16_t* __restrict__ Vt, float* __restrict__ attnW, bf16_t* __restrict__ ctx)
{
    constexpr int PITCH = 1036;
    __shared__ float S[16][PITCH];
    const int bh = blockIdx.x;              // bh-major: pins bh to one XCD
    const int qt = 63 - blockIdx.y;         // heaviest q-tiles first
    const int q0 = qt * 16;
    const int tid = threadIdx.x, w = tid >> 6, lane = tid & 63;
    const int lm = lane & 15, hi = lane >> 4;
    const int KT = qt + 1, KT16 = KT * 16;
    const int ZB = (KT16 + 255) & ~255;     // phase-B write bound / phase-A fill start

    // --- Phase A0: zero-fill masked attnW region [ZB, 1024) (fire-and-forget) ---
    {
        const f32x4 z4 = {0.f, 0.f, 0.f, 0.f};
#pragma unroll
        for (int rr = 0; rr < 4; ++rr) {
            float* arow = attnW + ((size_t)bh * Sdim + q0 + w * 4 + rr) * Sdim;
            for (int cb = ZB; cb < Sdim; cb += 256)
                *(f32x4*)(arow + cb + lane * 4) = z4;
        }
    }

    // --- Phase A: scores (x8), causal-masked -> S; 2 k-tiles in flight ---
    const size_t qoff = ((size_t)bh * Sdim + q0 + lm) * 64 + hi * 8;
    const bf16x8 qh0 = *(const bf16x8*)(Qhi + qoff);
    const bf16x8 qh1 = *(const bf16x8*)(Qhi + qoff + 32);
    const bf16x8 ql0 = *(const bf16x8*)(Qlo + qoff);
    const bf16x8 ql1 = *(const bf16x8*)(Qlo + qoff + 32);

    const bf16_t* Khb = Khi + (size_t)bh * Sdim * 64;
    const bf16_t* Klb = Klo + (size_t)bh * Sdim * 64;

    for (int kt = w; kt < KT; kt += 8) {
        const size_t o1 = (size_t)(kt * 16 + lm) * 64 + hi * 8;
        const bf16x8 kh0a = *(const bf16x8*)(Khb + o1);
        const bf16x8 kh1a = *(const bf16x8*)(Khb + o1 + 32);
        const bf16x8 kl0a = *(const bf16x8*)(Klb + o1);
        const bf16x8 kl1a = *(const bf16x8*)(Klb + o1 + 32);
        const int kt2 = kt + 4;
        const bool has2 = (kt2 < KT);
        bf16x8 kh0b = kh0a, kh1b = kh1a, kl0b = kl0a, kl1b = kl1a;
        if (has2) {
            const size_t o2 = (size_t)(kt2 * 16 + lm) * 64 + hi * 8;
            kh0b = *(const bf16x8*)(Khb + o2);
            kh1b = *(const bf16x8*)(Khb + o2 + 32);
            kl0b = *(const bf16x8*)(Klb + o2);
            kl1b = *(const bf16x8*)(Klb + o2 + 32);
        }
        f32x4 t0 = {0.f, 0.f, 0.f, 0.f}, t1 = {0.f, 0.f, 0.f, 0.f};
        t0 = MFMA16(ql0, kh0a, t0, 0, 0, 0);
        t1 = MFMA16(ql0, kh0b, t1, 0, 0, 0);
        t0 = MFMA16(ql1, kh1a, t0, 0, 0, 0);
        t1 = MFMA16(ql1, kh1b, t1, 0, 0, 0);
        t0 = MFMA16(qh0, kl0a, t0, 0, 0, 0);
        t1 = MFMA16(qh0, kl0b, t1, 0, 0, 0);
        t0 = MFMA16(qh1, kl1a, t0, 0, 0, 0);
        t1 = MFMA16(qh1, kl1b, t1, 0, 0, 0);
        t0 = MFMA16(qh0, kh0a, t0, 0, 0, 0);
        t1 = MFMA16(qh0, kh0b, t1, 0, 0, 0);
        t0 = MFMA16(qh1, kh1a, t0, 0, 0, 0);
        t1 = MFMA16(qh1, kh1b, t1, 0, 0, 0);
        const int c1 = kt * 16 + lm;
#pragma unroll
        for (int j = 0; j < 4; ++j) {
            const int r = hi * 4 + j;
            S[r][c1] = (c1 <= q0 + r) ? t0[j] * 8.0f : MASKV;
        }
        if (has2) {
            const int c2 = kt2 * 16 + lm;
#pragma unroll
            for (int j = 0; j < 4; ++j) {
                const int r = hi * 4 + j;
                S[r][c2] = (c2 <= q0 + r) ? t1[j] * 8.0f : MASKV;
            }
        }
    }
    __syncthreads();

    // --- Phase B: softmax per row over [0, KT16); write weights [0, ZB) ---
#pragma unroll
    for (int rr = 0; rr < 4; ++rr) {
        const int r = w * 4 + rr;
        float mx = MASKV;
        for (int cb = 0; cb < KT16; cb += 256) {
            const int c = cb + lane * 4;
            const f32x4 v = *(const f32x4*)&S[r][c];
#pragma unroll
            for (int cc = 0; cc < 4; ++cc)
                if (c + cc < KT16) mx = fmaxf(mx, v[cc]);
        }
#pragma unroll
        for (int dd = 1; dd < 64; dd <<= 1) mx = fmaxf(mx, __shfl_xor(mx, dd));

        float z = 0.f;
        for (int cb = 0; cb < ZB; cb += 256) {
            const int c = cb + lane * 4;
            const f32x4 v = *(const f32x4*)&S[r][c];
            f32x4 e;
#pragma unroll
            for (int cc = 0; cc < 4; ++cc) {
                const float a = fmaxf(v[cc] - mx, -87.0f);
                const float ev = (c + cc < KT16) ? __expf(a) : 0.f;
                e[cc] = ev; z += ev;
            }
            *(f32x4*)&S[r][c] = e;
        }
#pragma unroll
        for (int dd = 1; dd < 64; dd <<= 1) z += __shfl_xor(z, dd);
        const float invZ = 1.0f / z;

        float* arow = attnW + ((size_t)bh * Sdim + q0 + r) * Sdim;
        for (int cb = 0; cb < ZB; cb += 256) {
            const int c = cb + lane * 4;
            const f32x4 e = *(const f32x4*)&S[r][c];
            f32x4 p;
#pragma unroll
            for (int cc = 0; cc < 4; ++cc) p[cc] = e[cc] * invZ;
            *(f32x4*)&S[r][c] = p;
            *(f32x4*)(arow + c) = p;
        }
        // pad S to 32-col boundary for phase C when KT is odd
        if ((KT16 & 31) && lane < 16) S[r][KT16 + lane] = 0.f;
    }
    __syncthreads();

    // --- Phase C: ctx = P @ V (2 independent accumulators for ILP) ---
    f32x4 acc0 = {0.f, 0.f, 0.f, 0.f}, acc1 = {0.f, 0.f, 0.f, 0.f};
    const int steps = (KT16 + 31) >> 5;
    const bf16_t* vtp = Vt + ((size_t)bh * 64 + w * 16 + lm) * Sdim;
    for (int ks = 0; ks < steps; ks += 2) {
        {
            const int kb = ks * 32 + hi * 8;
            const f32x4 v0 = *(const f32x4*)&S[lm][kb];
            const f32x4 v1 = *(const f32x4*)&S[lm][kb + 4];
            bf16x8 a;
#pragma unroll
            for (int i = 0; i < 4; ++i) { a[i] = (bf16_t)v0[i]; a[i + 4] = (bf16_t)v1[i]; }
            acc0 = MFMA16(a, *(const bf16x8*)(vtp + kb), acc0, 0, 0, 0);
        }
        if (ks + 1 < steps) {
            const int kb = (ks + 1) * 32 + hi * 8;
            const f32x4 v0 = *(const f32x4*)&S[lm][kb];
            const f32x4 v1 = *(const f32x4*)&S[lm][kb + 4];
            bf16x8 a;
#pragma unroll
            for (int i = 0; i < 4; ++i) { a[i] = (bf16_t)v0[i]; a[i + 4] = (bf16_t)v1[i]; }
            acc1 = MFMA16(a, *(const bf16x8*)(vtp + kb), acc1, 0, 0, 0);
        }
    }
    const f32x4 acc = acc0 + acc1;
    const int bb = bh >> 4, h = bh & 15;
#pragma unroll
    for (int j = 0; j < 4; ++j) {
        const int s = q0 + hi * 4 + j;
        ctx[((size_t)bb * Sdim + s) * 1024 + h * 64 + w * 16 + lm] = (bf16_t)acc[j];
    }
}

// ---- output projection: bf16 MFMA, f32 out + bias ----
__global__ __launch_bounds__(256) void gemm_proj(
    const bf16_t* __restrict__ A, const bf16_t* __restrict__ Bw,
    const float* __restrict__ bias, float* __restrict__ out)
{
    __shared__ bf16_t As[128 * 32];
    __shared__ bf16_t Bs[128 * 32];
    const int tid = threadIdx.x, w = tid >> 6, lane = tid & 63;
    const int lm = lane & 15, hi = lane >> 4;
    const int wr = w >> 1, wc = w & 1;
    const int m0 = blockIdx.x * 128, n0 = blockIdx.y * 128;

    f32x4 acc[4][4] = {};
    for (int kt = 0; kt < 32; ++kt) {
        __syncthreads();
#pragma unroll
        for (int c = 0; c < 2; ++c) {
            const int j = c * 256 + tid;
            const int r = j >> 2, cg = (j & 3) << 3;
            const int base = (c * 256 + w * 64) * 8;
            gload16(A  + (size_t)(m0 + r) * 1024 + kt * 32 + cg, &As[base]);
            gload16(Bw + (size_t)(n0 + r) * 1024 + kt * 32 + cg, &Bs[base]);
        }
        __syncthreads();
        bf16x8 af[4], bfr[4];
#pragma unroll
        for (int mi = 0; mi < 4; ++mi)
            af[mi] = *(const bf16x8*)&As[(wr * 64 + mi * 16 + lm) * 32 + hi * 8];
#pragma unroll
        for (int ni = 0; ni < 4; ++ni)
            bfr[ni] = *(const bf16x8*)&Bs[(wc * 64 + ni * 16 + lm) * 32 + hi * 8];
#pragma unroll
        for (int mi = 0; mi < 4; ++mi)
#pragma unroll
            for (int ni = 0; ni < 4; ++ni)
                acc[mi][ni] = MFMA16(af[mi], bfr[ni], acc[mi][ni], 0, 0, 0);
    }
#pragma unroll
    for (int mi = 0; mi < 4; ++mi)
#pragma unroll
        for (int ni = 0; ni < 4; ++ni) {
            const int e = n0 + wc * 64 + ni * 16 + lm;
            const float bv = bias[e];
#pragma unroll
            for (int j = 0; j < 4; ++j) {
                const int m = m0 + wr * 64 + mi * 16 + hi * 4 + j;
                out[(size_t)m * 1024 + e] = acc[mi][ni][j] + bv;
            }
        }
}

extern "C" void kernel_launch(void* const* d_in, const int* in_sizes, int n_in,
                              void* d_out, int out_size, void* d_ws, size_t ws_size,
                              hipStream_t stream)
{
    const float* big[3] = {nullptr, nullptr, nullptr}; int nbig = 0;
    const float* Wqkv = nullptr; const float* Wproj = nullptr; const float* bproj = nullptr;
    for (int i = 0; i < n_in; ++i) {
        const int sz = in_sizes[i];
        if (sz == 4194304)      { if (nbig < 3) big[nbig++] = (const float*)d_in[i]; }
        else if (sz == 3145728) { Wqkv  = (const float*)d_in[i]; }
        else if (sz == 1048576) { Wproj = (const float*)d_in[i]; }
        else if (sz == 1024)    { bproj = (const float*)d_in[i]; }
    }
    const float* x = big[0];

    float* out   = (float*)d_out;                        // f32 [B,S,D]
    float* attnW = out + (size_t)4194304;                // f32 [B,H,S,S] weights

    // Park input split planes in the attn region (consumed before attn_k writes)
    bf16_t* xh = (bf16_t*)attnW;
    bf16_t* xl = xh + (size_t)4194304;
    bf16_t* wh = xl + (size_t)4194304;
    bf16_t* wl = wh + (size_t)3145728;                   // 28 MB < 256 MB

    char* wsb = (char*)d_ws;                             // 50 MB used
    bf16_t* Qhi = (bf16_t*)wsb;                          // 8 MB [B,H,S,DH]
    bf16_t* Qlo = (bf16_t*)(wsb + ((size_t)8  << 20));   // 8 MB
    bf16_t* Khi = (bf16_t*)(wsb + ((size_t)16 << 20));   // 8 MB
    bf16_t* Klo = (bf16_t*)(wsb + ((size_t)24 << 20));   // 8 MB
    bf16_t* Vt  = (bf16_t*)(wsb + ((size_t)32 << 20));   // 8 MB [B,H,DH,S]
    bf16_t* ctx = (bf16_t*)(wsb + ((size_t)40 << 20));   // 8 MB [B,S,D]
    bf16_t* wp  = (bf16_t*)(wsb + ((size_t)48 << 20));   // 2 MB

    split2_k<<<2048, 256, 0, stream>>>(x, Wqkv, Wproj, xh, xl, wh, wl, wp);
    gemm_qkv<<<dim3(32, 24), 256, 0, stream>>>(xh, xl, wh, wl, Qhi, Qlo, Khi, Klo, Vt);
    attn_k<<<dim3(64, 64), 256, 0, stream>>>(Qhi, Qlo, Khi, Klo, Vt, attnW, ctx);
    gemm_proj<<<dim3(32, 8), 256, 0, stream>>>(ctx, wp, bproj, out);
}

// Round 23
// 240.810 us; speedup vs baseline: 1.0643x; 1.0643x over previous
//
#include <hip/hip_runtime.h>
#include <hip/hip_bf16.h>

typedef __bf16 bf16_t;
typedef __bf16 bf16x8 __attribute__((ext_vector_type(8)));
typedef __bf16 bf16x4 __attribute__((ext_vector_type(4)));
typedef float f32x4 __attribute__((ext_vector_type(4)));
typedef unsigned int u32;

#define MFMA16 __builtin_amdgcn_mfma_f32_16x16x32_bf16
static constexpr float MASKV = -1.0e30f;
static constexpr int Sdim = 1024;

__device__ __forceinline__ void gload16(const void* g, void* l) {
    __builtin_amdgcn_global_load_lds((const __attribute__((address_space(1))) u32*)g,
                                     (__attribute__((address_space(3))) u32*)l, 16, 0, 0);
}

__device__ __forceinline__ void splt2(float v, bf16_t* h, bf16_t* l) {
    const bf16_t hv = (bf16_t)v;
    *h = hv; *l = (bf16_t)(v - (float)hv);
}

// ---- split f32 inputs into bf16 hi/lo planes (x, W_qkv) + bf16 W_proj ----
static constexpr int QX = 1048576;
static constexpr int QW = 786432;

__global__ __launch_bounds__(256) void split2_k(
    const float* __restrict__ x, const float* __restrict__ wqkv, const float* __restrict__ wproj,
    bf16_t* __restrict__ xh, bf16_t* __restrict__ xl,
    bf16_t* __restrict__ wh, bf16_t* __restrict__ wl, bf16_t* __restrict__ wp)
{
    int q = blockIdx.x * 256 + threadIdx.x;
    const int stride = 2048 * 256;
#pragma unroll
    for (int it = 0; it < 4; ++it, q += stride) {
        if (q < QX + QW) {
            const float* src; bf16_t *dh, *dl;
            if (q < QX) { src = x + (size_t)q * 4; dh = xh + (size_t)q * 4; dl = xl + (size_t)q * 4; }
            else { const int r = q - QX; src = wqkv + (size_t)r * 4; dh = wh + (size_t)r * 4; dl = wl + (size_t)r * 4; }
            const f32x4 v = *(const f32x4*)src;
            bf16x4 hv, lv;
#pragma unroll
            for (int c = 0; c < 4; ++c) { bf16_t a, b; splt2(v[c], &a, &b); hv[c] = a; lv[c] = b; }
            *(bf16x4*)dh = hv; *(bf16x4*)dl = lv;
        } else {
            const int r = q - QX - QW;
            const f32x4 v = *(const f32x4*)(wproj + (size_t)r * 4);
            bf16x4 hv;
#pragma unroll
            for (int c = 0; c < 4; ++c) hv[c] = (bf16_t)v[c];
            *(bf16x4*)(wp + (size_t)r * 4) = hv;
        }
    }
}

// ---- QKV GEMM: hi/lo 3-product for Q/K -> PRE-SPLIT bf16 planes; V -> bf16 T ----
__global__ __launch_bounds__(256) void gemm_qkv(
    const bf16_t* __restrict__ Ah_g, const bf16_t* __restrict__ Al_g,
    const bf16_t* __restrict__ Bh_g, const bf16_t* __restrict__ Bl_g,
    bf16_t* __restrict__ Qhi, bf16_t* __restrict__ Qlo,
    bf16_t* __restrict__ Khi, bf16_t* __restrict__ Klo, bf16_t* __restrict__ Vt)
{
    __shared__ bf16_t Ah[128 * 32], Al[128 * 32], Bh[128 * 32], Bl[128 * 32];
    const int tid = threadIdx.x, w = tid >> 6, lane = tid & 63;
    const int lm = lane & 15, hi = lane >> 4;
    const int wr = w >> 1, wc = w & 1;
    const int m0 = blockIdx.x * 128, n0 = blockIdx.y * 128;
    const int isel = n0 >> 10;
    const bool three = (isel < 2);

    f32x4 acc[4][4] = {};

    for (int kt = 0; kt < 32; ++kt) {
        __syncthreads();
#pragma unroll
        for (int c = 0; c < 2; ++c) {
            const int j = c * 256 + tid;
            const int r = j >> 2, cg = (j & 3) << 3;
            const int base = (c * 256 + w * 64) * 8;
            const size_t goa = (size_t)(m0 + r) * 1024 + kt * 32 + cg;
            const size_t gob = (size_t)(n0 + r) * 1024 + kt * 32 + cg;
            gload16(Ah_g + goa, &Ah[base]);
            gload16(Bh_g + gob, &Bh[base]);
            if (three) {
                gload16(Al_g + goa, &Al[base]);
                gload16(Bl_g + gob, &Bl[base]);
            }
        }
        __syncthreads();

        bf16x8 ah[4], bh[4], al[4], bl[4];
#pragma unroll
        for (int mi = 0; mi < 4; ++mi)
            ah[mi] = *(const bf16x8*)&Ah[(wr * 64 + mi * 16 + lm) * 32 + hi * 8];
#pragma unroll
        for (int ni = 0; ni < 4; ++ni)
            bh[ni] = *(const bf16x8*)&Bh[(wc * 64 + ni * 16 + lm) * 32 + hi * 8];
        if (three) {
#pragma unroll
            for (int mi = 0; mi < 4; ++mi)
                al[mi] = *(const bf16x8*)&Al[(wr * 64 + mi * 16 + lm) * 32 + hi * 8];
#pragma unroll
            for (int ni = 0; ni < 4; ++ni)
                bl[ni] = *(const bf16x8*)&Bl[(wc * 64 + ni * 16 + lm) * 32 + hi * 8];
        }
#pragma unroll
        for (int mi = 0; mi < 4; ++mi)
#pragma unroll
            for (int ni = 0; ni < 4; ++ni) {
                if (three) {
                    acc[mi][ni] = MFMA16(ah[mi], bl[ni], acc[mi][ni], 0, 0, 0);
                    acc[mi][ni] = MFMA16(al[mi], bh[ni], acc[mi][ni], 0, 0, 0);
                }
                acc[mi][ni] = MFMA16(ah[mi], bh[ni], acc[mi][ni], 0, 0, 0);
            }
    }

#pragma unroll
    for (int mi = 0; mi < 4; ++mi)
#pragma unroll
        for (int ni = 0; ni < 4; ++ni)
#pragma unroll
            for (int j = 0; j < 4; ++j) {
                const float v = acc[mi][ni][j];
                const int m = m0 + wr * 64 + mi * 16 + hi * 4 + j;
                const int e = n0 + wc * 64 + ni * 16 + lm;
                const int b = m >> 10, s = m & 1023;
                const int h = (e >> 6) & 15, dh = e & 63;
                if (isel < 2) {
                    const size_t off = (((size_t)(b * 16 + h)) * Sdim + s) * 64 + dh;
                    bf16_t hv, lv; splt2(v, &hv, &lv);
                    if (isel == 0) { Qhi[off] = hv; Qlo[off] = lv; }
                    else           { Khi[off] = hv; Klo[off] = lv; }
                } else {
                    Vt[(((size_t)(b * 16 + h)) * 64 + dh) * Sdim + s] = (bf16_t)v;
                }
            }
}

// ---- fused attention: 8-wave blocks (2x occupancy), spread writes, bounded softmax ----
__global__ __launch_bounds__(512) void attn_k(
    const bf16_t* __restrict__ Qhi, const bf16_t* __restrict__ Qlo,
    const bf16_t* __restrict__ Khi, const bf16_t* __restrict__ Klo,
    const bf16_t* __restrict__ Vt, float* __restrict__ attnW, bf16_t* __restrict__ ctx)
{
    constexpr int PITCH = 1036;
    __shared__ float S[16][PITCH];
    const int bh = blockIdx.x;              // bh-major: pins bh to one XCD
    const int qt = 63 - blockIdx.y;         // heaviest q-tiles first
    const int q0 = qt * 16;
    const int tid = threadIdx.x, w = tid >> 6, lane = tid & 63;
    const int lm = lane & 15, hi = lane >> 4;
    const int KT = qt + 1, KT16 = KT * 16;
    const int ZB = (KT16 + 255) & ~255;

    // --- Phase A0: zero-fill masked attnW region [ZB, 1024); 2 rows per wave ---
    {
        const f32x4 z4 = {0.f, 0.f, 0.f, 0.f};
#pragma unroll
        for (int rr = 0; rr < 2; ++rr) {
            float* arow = attnW + ((size_t)bh * Sdim + q0 + w * 2 + rr) * Sdim;
            for (int cb = ZB; cb < Sdim; cb += 256)
                *(f32x4*)(arow + cb + lane * 4) = z4;
        }
    }

    // --- Phase A: scores (x8), causal-masked -> S; k-tiles striped over 8 waves ---
    const size_t qoff = ((size_t)bh * Sdim + q0 + lm) * 64 + hi * 8;
    const bf16x8 qh0 = *(const bf16x8*)(Qhi + qoff);
    const bf16x8 qh1 = *(const bf16x8*)(Qhi + qoff + 32);
    const bf16x8 ql0 = *(const bf16x8*)(Qlo + qoff);
    const bf16x8 ql1 = *(const bf16x8*)(Qlo + qoff + 32);

    const bf16_t* Khb = Khi + (size_t)bh * Sdim * 64;
    const bf16_t* Klb = Klo + (size_t)bh * Sdim * 64;

    for (int kt = w; kt < KT; kt += 16) {
        const size_t o1 = (size_t)(kt * 16 + lm) * 64 + hi * 8;
        const bf16x8 kh0a = *(const bf16x8*)(Khb + o1);
        const bf16x8 kh1a = *(const bf16x8*)(Khb + o1 + 32);
        const bf16x8 kl0a = *(const bf16x8*)(Klb + o1);
        const bf16x8 kl1a = *(const bf16x8*)(Klb + o1 + 32);
        const int kt2 = kt + 8;
        const bool has2 = (kt2 < KT);
        bf16x8 kh0b = kh0a, kh1b = kh1a, kl0b = kl0a, kl1b = kl1a;
        if (has2) {
            const size_t o2 = (size_t)(kt2 * 16 + lm) * 64 + hi * 8;
            kh0b = *(const bf16x8*)(Khb + o2);
            kh1b = *(const bf16x8*)(Khb + o2 + 32);
            kl0b = *(const bf16x8*)(Klb + o2);
            kl1b = *(const bf16x8*)(Klb + o2 + 32);
        }
        f32x4 t0 = {0.f, 0.f, 0.f, 0.f}, t1 = {0.f, 0.f, 0.f, 0.f};
        t0 = MFMA16(ql0, kh0a, t0, 0, 0, 0);
        t1 = MFMA16(ql0, kh0b, t1, 0, 0, 0);
        t0 = MFMA16(ql1, kh1a, t0, 0, 0, 0);
        t1 = MFMA16(ql1, kh1b, t1, 0, 0, 0);
        t0 = MFMA16(qh0, kl0a, t0, 0, 0, 0);
        t1 = MFMA16(qh0, kl0b, t1, 0, 0, 0);
        t0 = MFMA16(qh1, kl1a, t0, 0, 0, 0);
        t1 = MFMA16(qh1, kl1b, t1, 0, 0, 0);
        t0 = MFMA16(qh0, kh0a, t0, 0, 0, 0);
        t1 = MFMA16(qh0, kh0b, t1, 0, 0, 0);
        t0 = MFMA16(qh1, kh1a, t0, 0, 0, 0);
        t1 = MFMA16(qh1, kh1b, t1, 0, 0, 0);
        const int c1 = kt * 16 + lm;
#pragma unroll
        for (int j = 0; j < 4; ++j) {
            const int r = hi * 4 + j;
            S[r][c1] = (c1 <= q0 + r) ? t0[j] * 8.0f : MASKV;
        }
        if (has2) {
            const int c2 = kt2 * 16 + lm;
#pragma unroll
            for (int j = 0; j < 4; ++j) {
                const int r = hi * 4 + j;
                S[r][c2] = (c2 <= q0 + r) ? t1[j] * 8.0f : MASKV;
            }
        }
    }
    __syncthreads();

    // --- Phase B: softmax, 2 rows per wave; write weights [0, ZB) ---
#pragma unroll
    for (int rr = 0; rr < 2; ++rr) {
        const int r = w * 2 + rr;
        float mx = MASKV;
        for (int cb = 0; cb < KT16; cb += 256) {
            const int c = cb + lane * 4;
            const f32x4 v = *(const f32x4*)&S[r][c];
#pragma unroll
            for (int cc = 0; cc < 4; ++cc)
                if (c + cc < KT16) mx = fmaxf(mx, v[cc]);
        }
#pragma unroll
        for (int dd = 1; dd < 64; dd <<= 1) mx = fmaxf(mx, __shfl_xor(mx, dd));

        float z = 0.f;
        for (int cb = 0; cb < ZB; cb += 256) {
            const int c = cb + lane * 4;
            const f32x4 v = *(const f32x4*)&S[r][c];
            f32x4 e;
#pragma unroll
            for (int cc = 0; cc < 4; ++cc) {
                const float a = fmaxf(v[cc] - mx, -87.0f);
                const float ev = (c + cc < KT16) ? __expf(a) : 0.f;
                e[cc] = ev; z += ev;
            }
            *(f32x4*)&S[r][c] = e;
        }
#pragma unroll
        for (int dd = 1; dd < 64; dd <<= 1) z += __shfl_xor(z, dd);
        const float invZ = 1.0f / z;

        float* arow = attnW + ((size_t)bh * Sdim + q0 + r) * Sdim;
        for (int cb = 0; cb < ZB; cb += 256) {
            const int c = cb + lane * 4;
            const f32x4 e = *(const f32x4*)&S[r][c];
            f32x4 p;
#pragma unroll
            for (int cc = 0; cc < 4; ++cc) p[cc] = e[cc] * invZ;
            *(f32x4*)&S[r][c] = p;
            *(f32x4*)(arow + c) = p;
        }
        if ((KT16 & 31) && lane < 16) S[r][KT16 + lane] = 0.f;
    }
    __syncthreads();

    // --- Phase C: ctx = P @ V (waves 0-3 only; unchanged mapping) ---
    if (w < 4) {
        f32x4 acc0 = {0.f, 0.f, 0.f, 0.f}, acc1 = {0.f, 0.f, 0.f, 0.f};
        const int steps = (KT16 + 31) >> 5;
        const bf16_t* vtp = Vt + ((size_t)bh * 64 + w * 16 + lm) * Sdim;
        for (int ks = 0; ks < steps; ks += 2) {
            {
                const int kb = ks * 32 + hi * 8;
                const f32x4 v0 = *(const f32x4*)&S[lm][kb];
                const f32x4 v1 = *(const f32x4*)&S[lm][kb + 4];
                bf16x8 a;
#pragma unroll
                for (int i = 0; i < 4; ++i) { a[i] = (bf16_t)v0[i]; a[i + 4] = (bf16_t)v1[i]; }
                acc0 = MFMA16(a, *(const bf16x8*)(vtp + kb), acc0, 0, 0, 0);
            }
            if (ks + 1 < steps) {
                const int kb = (ks + 1) * 32 + hi * 8;
                const f32x4 v0 = *(const f32x4*)&S[lm][kb];
                const f32x4 v1 = *(const f32x4*)&S[lm][kb + 4];
                bf16x8 a;
#pragma unroll
                for (int i = 0; i < 4; ++i) { a[i] = (bf16_t)v0[i]; a[i + 4] = (bf16_t)v1[i]; }
                acc1 = MFMA16(a, *(const bf16x8*)(vtp + kb), acc1, 0, 0, 0);
            }
        }
        const f32x4 acc = acc0 + acc1;
        const int bb = bh >> 4, h = bh & 15;
#pragma unroll
        for (int j = 0; j < 4; ++j) {
            const int s = q0 + hi * 4 + j;
            ctx[((size_t)bb * Sdim + s) * 1024 + h * 64 + w * 16 + lm] = (bf16_t)acc[j];
        }
    }
}

// ---- output projection: bf16 MFMA, f32 out + bias ----
__global__ __launch_bounds__(256) void gemm_proj(
    const bf16_t* __restrict__ A, const bf16_t* __restrict__ Bw,
    const float* __restrict__ bias, float* __restrict__ out)
{
    __shared__ bf16_t As[128 * 32];
    __shared__ bf16_t Bs[128 * 32];
    const int tid = threadIdx.x, w = tid >> 6, lane = tid & 63;
    const int lm = lane & 15, hi = lane >> 4;
    const int wr = w >> 1, wc = w & 1;
    const int m0 = blockIdx.x * 128, n0 = blockIdx.y * 128;

    f32x4 acc[4][4] = {};
    for (int kt = 0; kt < 32; ++kt) {
        __syncthreads();
#pragma unroll
        for (int c = 0; c < 2; ++c) {
            const int j = c * 256 + tid;
            const int r = j >> 2, cg = (j & 3) << 3;
            const int base = (c * 256 + w * 64) * 8;
            gload16(A  + (size_t)(m0 + r) * 1024 + kt * 32 + cg, &As[base]);
            gload16(Bw + (size_t)(n0 + r) * 1024 + kt * 32 + cg, &Bs[base]);
        }
        __syncthreads();
        bf16x8 af[4], bfr[4];
#pragma unroll
        for (int mi = 0; mi < 4; ++mi)
            af[mi] = *(const bf16x8*)&As[(wr * 64 + mi * 16 + lm) * 32 + hi * 8];
#pragma unroll
        for (int ni = 0; ni < 4; ++ni)
            bfr[ni] = *(const bf16x8*)&Bs[(wc * 64 + ni * 16 + lm) * 32 + hi * 8];
#pragma unroll
        for (int mi = 0; mi < 4; ++mi)
#pragma unroll
            for (int ni = 0; ni < 4; ++ni)
                acc[mi][ni] = MFMA16(af[mi], bfr[ni], acc[mi][ni], 0, 0, 0);
    }
#pragma unroll
    for (int mi = 0; mi < 4; ++mi)
#pragma unroll
        for (int ni = 0; ni < 4; ++ni) {
            const int e = n0 + wc * 64 + ni * 16 + lm;
            const float bv = bias[e];
#pragma unroll
            for (int j = 0; j < 4; ++j) {
                const int m = m0 + wr * 64 + mi * 16 + hi * 4 + j;
                out[(size_t)m * 1024 + e] = acc[mi][ni][j] + bv;
            }
        }
}

extern "C" void kernel_launch(void* const* d_in, const int* in_sizes, int n_in,
                              void* d_out, int out_size, void* d_ws, size_t ws_size,
                              hipStream_t stream)
{
    const float* big[3] = {nullptr, nullptr, nullptr}; int nbig = 0;
    const float* Wqkv = nullptr; const float* Wproj = nullptr; const float* bproj = nullptr;
    for (int i = 0; i < n_in; ++i) {
        const int sz = in_sizes[i];
        if (sz == 4194304)      { if (nbig < 3) big[nbig++] = (const float*)d_in[i]; }
        else if (sz == 3145728) { Wqkv  = (const float*)d_in[i]; }
        else if (sz == 1048576) { Wproj = (const float*)d_in[i]; }
        else if (sz == 1024)    { bproj = (const float*)d_in[i]; }
    }
    const float* x = big[0];

    float* out   = (float*)d_out;                        // f32 [B,S,D]
    float* attnW = out + (size_t)4194304;                // f32 [B,H,S,S] weights

    bf16_t* xh = (bf16_t*)attnW;
    bf16_t* xl = xh + (size_t)4194304;
    bf16_t* wh = xl + (size_t)4194304;
    bf16_t* wl = wh + (size_t)3145728;

    char* wsb = (char*)d_ws;
    bf16_t* Qhi = (bf16_t*)wsb;
    bf16_t* Qlo = (bf16_t*)(wsb + ((size_t)8  << 20));
    bf16_t* Khi = (bf16_t*)(wsb + ((size_t)16 << 20));
    bf16_t* Klo = (bf16_t*)(wsb + ((size_t)24 << 20));
    bf16_t* Vt  = (bf16_t*)(wsb + ((size_t)32 << 20));
    bf16_t* ctx = (bf16_t*)(wsb + ((size_t)40 << 20));
    bf16_t* wp  = (bf16_t*)(wsb + ((size_t)48 << 20));

    split2_k<<<2048, 256, 0, stream>>>(x, Wqkv, Wproj, xh, xl, wh, wl, wp);
    gemm_qkv<<<dim3(32, 24), 256, 0, stream>>>(xh, xl, wh, wl, Qhi, Qlo, Khi, Klo, Vt);
    attn_k<<<dim3(64, 64), 512, 0, stream>>>(Qhi, Qlo, Khi, Klo, Vt, attnW, ctx);
    gemm_proj<<<dim3(32, 8), 256, 0, stream>>>(ctx, wp, bproj, out);
}